// Round 12
// baseline (2657.955 us; speedup 1.0000x reference)
//
#include <hip/hip_runtime.h>
#include <hip/hip_bf16.h>

#define N_EDGES_C 1000000
#define EDGE_DIM_C 64
#define NODE_DIM_C 64
#define IN_DIM_C   192
#define HID_C      256
#define N_TILES    31250      // 32-edge wave-tiles
#define GRID_BLKS  512        // 8 waves each -> 4096 independent waves

typedef __attribute__((ext_vector_type(8))) short  short8;
typedef __attribute__((ext_vector_type(4))) float  f32x4;

__device__ __forceinline__ unsigned short f2bf(float f) {
    union { float f; unsigned u; } v; v.f = f;
    unsigned u = v.u;
    u += 0x7fffu + ((u >> 16) & 1u);   // round-to-nearest-even
    return (unsigned short)(u >> 16);
}

// sigma: acc1 slot r = nt*16 + lg*4 + j  ->  original feature
//        f = (nt>>1)*32 + lg*8 + (nt&1)*4 + j
// With W1 rows permuted by sigma, lane-local acc1 slots (2kb,2kb+1) form the
// L2 B-fragment (8 consecutive k) directly -- H never leaves registers.
__device__ __forceinline__ int sigma_feat(int r) {
    return ((r >> 5) << 5) | (((r >> 2) & 3) << 3) | (((r >> 4) & 1) << 2) | (r & 3);
}

// W1[192][256] -> W1Tn bf16 [256 rows sigma-permuted][192]
// W2[256][256] -> W2T  bf16 [256][256] (plain transpose)
// b1[256]      -> b1p  f32  [256] sigma-permuted
__global__ void prep_weights_kernel(const float* __restrict__ W1,
                                    const float* __restrict__ W2,
                                    const float* __restrict__ b1,
                                    unsigned short* __restrict__ W1Tn,
                                    unsigned short* __restrict__ W2T,
                                    float* __restrict__ b1p) {
    int tid = blockIdx.x * 256 + threadIdx.x;
    if (tid < IN_DIM_C * HID_C) {                       // 49152
        int r = tid / IN_DIM_C, k = tid - r * IN_DIM_C;
        W1Tn[tid] = f2bf(W1[k * HID_C + sigma_feat(r)]);
    } else if (tid < IN_DIM_C * HID_C + HID_C * HID_C) { // +65536
        int t2 = tid - IN_DIM_C * HID_C;
        int o = t2 >> 8, k = t2 & 255;
        W2T[t2] = f2bf(W2[k * HID_C + o]);
    } else if (tid < IN_DIM_C * HID_C + HID_C * HID_C + HID_C) {
        int r = tid - IN_DIM_C * HID_C - HID_C * HID_C;
        b1p[r] = b1[sigma_feat(r)];
    }
}

// 512 threads = 8 INDEPENDENT waves. One __syncthreads after W2->LDS staging,
// then zero barriers: each wave grid-strides over 32-edge tiles on its own.
// Per tile per wave:
//   X: 24 f32x4 direct global->reg in B-frag layout (no LDS)
//   L1: A = W1Tn streamed from L2 (96KB hot), B = X regs -> acc1 (sigma'd)
//   H: bias+relu+cvt in regs (lane-local, zero shuffle)
//   L2: A = W2 from LDS (XOR-swizzled), B = H regs -> acc2
//   store: NT f32x4; same wave covers full 1KB rows (ot ascending -> merge)
__global__ __launch_bounds__(512, 2) void edge_mlp_kernel(
    const float* __restrict__ E, const float* __restrict__ V,
    const int* __restrict__ srcI, const int* __restrict__ dstI,
    const unsigned short* __restrict__ W1Tn, const float* __restrict__ b1p,
    const unsigned short* __restrict__ W2T, const float* __restrict__ b2,
    float* __restrict__ out)
{
    __shared__ unsigned char w2s[131072];   // W2 bf16 [256][256], swizzled
    const int tid = threadIdx.x;

    // ---- stage W2 -> LDS once (row r, 16B chunk cb: byte = r*512 + (cb^((r&7)<<4))) ----
#pragma unroll
    for (int i = 0; i < 16; ++i) {
        int c  = tid + i * 512;             // 16B-chunk id 0..8191
        int r  = c >> 5;
        int cb = (c & 31) << 4;
        short8 v = *reinterpret_cast<const short8*>(W2T + (size_t)c * 8);
        *reinterpret_cast<short8*>(w2s + r * 512 + (cb ^ ((r & 7) << 4))) = v;
    }
    __syncthreads();                        // the ONLY block-wide barrier

    const int l    = tid & 63;
    const int lm   = l & 15;
    const int lg   = l >> 4;
    const int col8 = lg * 8;                // k-offset within a 32-block
    const int swz  = (lm & 7) << 4;
    const int gw   = blockIdx.x * 8 + (tid >> 6);
    const int nw   = GRID_BLKS * 8;

    for (int tile = gw; tile < N_TILES; tile += nw) {
        const long eb = (long)tile * 32;

        // ---- gather indices (lane-redundant x4 over lg, coalesced) ----
        int si[2], di[2];
        si[0] = srcI[eb + lm];      si[1] = srcI[eb + 16 + lm];
        di[0] = dstI[eb + lm];      di[1] = dstI[eb + 16 + lm];

        // ---- X frags: direct global -> reg (B-frag layout) ----
        short8 xf[2][6];
#pragma unroll
        for (int mt = 0; mt < 2; ++mt) {
            const float* ep = E + (size_t)(eb + mt * 16 + lm) * EDGE_DIM_C;
            const float* vs = V + (size_t)si[mt] * NODE_DIM_C;
            const float* vd = V + (size_t)di[mt] * NODE_DIM_C;
#pragma unroll
            for (int kb = 0; kb < 6; ++kb) {
                f32x4 a, b;
                if (kb < 2) {       // E features 0..63: NT (stream-once)
                    a = __builtin_nontemporal_load(
                        reinterpret_cast<const f32x4*>(ep + kb * 32 + col8));
                    b = __builtin_nontemporal_load(
                        reinterpret_cast<const f32x4*>(ep + kb * 32 + col8 + 4));
                } else if (kb < 4) { // V[src] features 64..127: cacheable
                    a = *reinterpret_cast<const f32x4*>(vs + (kb - 2) * 32 + col8);
                    b = *reinterpret_cast<const f32x4*>(vs + (kb - 2) * 32 + col8 + 4);
                } else {             // V[dst] features 128..191
                    a = *reinterpret_cast<const f32x4*>(vd + (kb - 4) * 32 + col8);
                    b = *reinterpret_cast<const f32x4*>(vd + (kb - 4) * 32 + col8 + 4);
                }
                short8 t;
                t[0] = f2bf(a[0]); t[1] = f2bf(a[1]); t[2] = f2bf(a[2]); t[3] = f2bf(a[3]);
                t[4] = f2bf(b[0]); t[5] = f2bf(b[1]); t[6] = f2bf(b[2]); t[7] = f2bf(b[3]);
                xf[mt][kb] = t;
            }
        }

        // ---- Layer 1: A = W1Tn (global, L2-hot), B = xf ----
        f32x4 acc1[2][16];
#pragma unroll
        for (int m = 0; m < 2; ++m)
#pragma unroll
            for (int n = 0; n < 16; ++n) acc1[m][n] = (f32x4){0.f, 0.f, 0.f, 0.f};

#pragma unroll
        for (int kb = 0; kb < 6; ++kb) {
#pragma unroll
            for (int h = 0; h < 2; ++h) {   // split nt 16 -> 2x8 (reg pressure)
                short8 aw[8];
#pragma unroll
                for (int o = 0; o < 8; ++o)
                    aw[o] = *reinterpret_cast<const short8*>(
                        W1Tn + (size_t)((h * 8 + o) * 16 + lm) * IN_DIM_C + kb * 32 + col8);
#pragma unroll
                for (int o = 0; o < 8; ++o)
#pragma unroll
                    for (int mt = 0; mt < 2; ++mt)
                        acc1[mt][h * 8 + o] = __builtin_amdgcn_mfma_f32_16x16x32_bf16(
                            aw[o], xf[mt][kb], acc1[mt][h * 8 + o], 0, 0, 0);
            }
        }

        // ---- H: bias + relu + cvt, fully lane-local (sigma trick) ----
        short8 hf[2][8];
#pragma unroll
        for (int nt = 0; nt < 16; ++nt) {
            f32x4 bb = *reinterpret_cast<const f32x4*>(b1p + nt * 16 + lg * 4);
#pragma unroll
            for (int mt = 0; mt < 2; ++mt) {
#pragma unroll
                for (int j = 0; j < 4; ++j)
                    hf[mt][nt >> 1][(nt & 1) * 4 + j] =
                        (short)f2bf(fmaxf(acc1[mt][nt][j] + bb[j], 0.f));
            }
        }

        // ---- Layer 2: A = W2 (LDS, swizzled), B = hf ----
        f32x4 acc2[2][16];
#pragma unroll
        for (int m = 0; m < 2; ++m)
#pragma unroll
            for (int n = 0; n < 16; ++n) acc2[m][n] = (f32x4){0.f, 0.f, 0.f, 0.f};

#pragma unroll
        for (int kb = 0; kb < 8; ++kb) {
#pragma unroll
            for (int h = 0; h < 2; ++h) {
                short8 aw[8];
#pragma unroll
                for (int o = 0; o < 8; ++o) {
                    int ot = h * 8 + o;
                    aw[o] = *reinterpret_cast<const short8*>(
                        w2s + (ot * 16 + lm) * 512 + ((kb * 64 + lg * 16) ^ swz));
                }
#pragma unroll
                for (int o = 0; o < 8; ++o)
#pragma unroll
                    for (int mt = 0; mt < 2; ++mt)
                        acc2[mt][h * 8 + o] = __builtin_amdgcn_mfma_f32_16x16x32_bf16(
                            aw[o], hf[mt][kb], acc2[mt][h * 8 + o], 0, 0, 0);
            }
        }

        // ---- store: +b2, NT f32x4; wave covers full rows (ot ascending) ----
#pragma unroll
        for (int ot = 0; ot < 16; ++ot) {
            f32x4 bb = *reinterpret_cast<const f32x4*>(b2 + ot * 16 + lg * 4);
#pragma unroll
            for (int mt = 0; mt < 2; ++mt) {
                f32x4 r = acc2[mt][ot] + bb;
                __builtin_nontemporal_store(r, reinterpret_cast<f32x4*>(
                    out + (size_t)(eb + mt * 16 + lm) * HID_C + ot * 16 + lg * 4));
            }
        }
    }
}

extern "C" void kernel_launch(void* const* d_in, const int* in_sizes, int n_in,
                              void* d_out, int out_size, void* d_ws, size_t ws_size,
                              hipStream_t stream) {
    const float* E  = (const float*)d_in[0];
    const float* V  = (const float*)d_in[1];
    const int*   ei = (const int*)d_in[2];   // [2][N_EDGES] int32
    const float* W1 = (const float*)d_in[3];
    const float* b1 = (const float*)d_in[4];
    const float* W2 = (const float*)d_in[5];
    const float* b2 = (const float*)d_in[6];
    float* out = (float*)d_out;

    unsigned short* W1Tn = (unsigned short*)d_ws;                  // 49152 bf16
    unsigned short* W2T  = W1Tn + IN_DIM_C * HID_C;                // 65536 bf16
    float*          b1p  = (float*)(W2T + HID_C * HID_C);          // 256 f32

    const int prep_total = IN_DIM_C * HID_C + HID_C * HID_C + HID_C; // 114944
    prep_weights_kernel<<<(prep_total + 255) / 256, 256, 0, stream>>>(
        W1, W2, b1, W1Tn, W2T, b1p);

    edge_mlp_kernel<<<GRID_BLKS, 512, 0, stream>>>(
        E, V, ei, ei + N_EDGES_C, W1Tn, b1p, W2T, b2, out);
}

// Round 13
// 575.342 us; speedup vs baseline: 4.6198x; 4.6198x over previous
//
#include <hip/hip_runtime.h>
#include <hip/hip_bf16.h>

#define N_EDGES_C 1000000
#define EDGE_DIM_C 64
#define NODE_DIM_C 64
#define IN_DIM_C   192
#define HID_C      256
#define XPAD 200            // bf16 elems per X row (192+8 pad) -> 400B rows
#define XBUF_SZ 25600       // 64 rows * 400B
#define HS_OFF  51200       // H buffers start after 2 X buffers
#define HBUF_SZ 32768       // 64 rows * 512B (swizzled)
#define T_TILES 5           // tiles of 64 edges; 15625/5 = 3125 blocks

typedef __attribute__((ext_vector_type(8))) short  short8;
typedef __attribute__((ext_vector_type(4))) float  f32x4;

// lgkm-drain barrier (writer-side visibility). Stores/prefetch loads stay
// in flight across it (T4).
#define BAR_LDS() asm volatile("s_waitcnt lgkmcnt(0)\n\ts_barrier" ::: "memory")
// Phase-alignment barrier (no drain): m201 pattern.
#define BAR()     asm volatile("s_barrier" ::: "memory")
// Wait own ds_reads, pin the boundary (rule #18), then MFMA cluster.
#define LGKM0()   do { asm volatile("s_waitcnt lgkmcnt(0)" ::: "memory"); \
                       __builtin_amdgcn_sched_barrier(0); } while (0)

__device__ __forceinline__ unsigned short f2bf(float f) {
    union { float f; unsigned u; } v; v.f = f;
    unsigned u = v.u;
    u += 0x7fffu + ((u >> 16) & 1u);   // round-to-nearest-even
    return (unsigned short)(u >> 16);
}

// W1[192][256] -> W1T bf16 [256][192]; W2[256][256] -> W2T bf16 [256][256].
__global__ void prep_weights_kernel(const float* __restrict__ W1,
                                    const float* __restrict__ W2,
                                    unsigned short* __restrict__ W1T,
                                    unsigned short* __restrict__ W2T) {
    int tid = blockIdx.x * 256 + threadIdx.x;
    if (tid < IN_DIM_C * HID_C) {
        int n = tid / IN_DIM_C, k = tid - n * IN_DIM_C;
        W1T[tid] = f2bf(W1[k * HID_C + n]);
    } else {
        int t2 = tid - IN_DIM_C * HID_C;
        if (t2 < HID_C * HID_C) {
            int o = t2 / HID_C, k = t2 - o * HID_C;
            W2T[t2] = f2bf(W2[k * HID_C + o]);
        }
    }
}

// 512 threads = 8 waves; wave w owns feature slice [w*32,+32) for BOTH layers,
// W1/W2 fragments reg-pinned once per block. Xs/Hs double-buffered.
// Per tile: 7 m201-style phases, each {8 ds_read_b128; BAR; lgkm0; setprio1;
// 16 MFMA; setprio0; BAR}, plus one epilogue/staging phase ending in BAR_LDS.
// Gathers for t+1 issue at tile top and stay in flight (counted vmcnt only).
__global__ __launch_bounds__(512, 2) void edge_mlp_kernel(
    const float* __restrict__ E, const float* __restrict__ V,
    const int* __restrict__ srcI, const int* __restrict__ dstI,
    const unsigned short* __restrict__ W1T, const float* __restrict__ b1,
    const unsigned short* __restrict__ W2T, const float* __restrict__ b2,
    float* __restrict__ out)
{
    __shared__ unsigned char smem[HS_OFF + 2 * HBUF_SZ];   // 116736 B
    const int tid = threadIdx.x;
    const int w  = tid >> 6;     // wave 0..7
    const int l  = tid & 63;
    const int lm = l & 15;
    const int lg = l >> 4;
    const long block0 = (long)blockIdx.x * (64 * T_TILES);

    // ---- weight fragments -> registers (once per block) ----
    short8 wA1[6][2];            // [kb][nt]
    short8 wA2[8][2];            // [kb][ot]
#pragma unroll
    for (int kb = 0; kb < 6; ++kb)
#pragma unroll
        for (int nt = 0; nt < 2; ++nt)
            wA1[kb][nt] = *reinterpret_cast<const short8*>(
                W1T + (size_t)(w * 32 + nt * 16 + lm) * IN_DIM_C + kb * 32 + lg * 8);
#pragma unroll
    for (int kb = 0; kb < 8; ++kb)
#pragma unroll
        for (int ot = 0; ot < 2; ++ot)
            wA2[kb][ot] = *reinterpret_cast<const short8*>(
                W2T + (size_t)(w * 32 + ot * 16 + lm) * HID_C + kb * 32 + lg * 8);

    // ---- reg-staged next-tile data (lives across barriers) ----
    f32x4 fE[2];   // wave's 8 E-rows x 64 f32
    f32x4 fV[4];   // wave's 8 (src,dst) V-rows

    const int kind = (l >> 3) & 1;               // 0:src 1:dst
    const int rr   = l & 7;
    const int* const ip = kind ? dstI : srcI;

    auto load_idx = [&](long tb) -> int {        // lanes 0-15: s0..7,d0..7
        return ip[tb + w * 8 + rr];
    };

    auto issueEV = [&](long tb, int myidx) {
#pragma unroll
        for (int i = 0; i < 2; ++i) {
            int f = i * 64 + l;                  // row f>>4 in 0..7
            fE[i] = __builtin_nontemporal_load(reinterpret_cast<const f32x4*>(
                E + (size_t)(tb + w * 8 + (f >> 4)) * EDGE_DIM_C + (f & 15) * 4));
        }
#pragma unroll
        for (int i = 0; i < 4; ++i) {
            int kind2 = ((l & 31) < 16) ? 0 : 1; // src / dst half of X row
            int srcl  = kind2 * 8 + i * 2 + (l >> 5);
            int gi = __builtin_amdgcn_ds_bpermute(srcl << 2, myidx);
            fV[i] = *reinterpret_cast<const f32x4*>(
                V + (size_t)gi * NODE_DIM_C + (l & 15) * 4);
        }
    };

    auto write_lds = [&](int buf) {
        unsigned short* Xw = (unsigned short*)(smem + buf * XBUF_SZ);
#pragma unroll
        for (int i = 0; i < 2; ++i) {
            int f = i * 64 + l;
            ushort4 b;
            b.x = f2bf(fE[i][0]); b.y = f2bf(fE[i][1]);
            b.z = f2bf(fE[i][2]); b.w = f2bf(fE[i][3]);
            *reinterpret_cast<ushort4*>(
                &Xw[(w * 8 + (f >> 4)) * XPAD + (f & 15) * 4]) = b;
        }
#pragma unroll
        for (int i = 0; i < 4; ++i) {
            int kind2 = ((l & 31) < 16) ? 0 : 1;
            int rV    = i * 2 + (l >> 5);
            ushort4 b;
            b.x = f2bf(fV[i][0]); b.y = f2bf(fV[i][1]);
            b.z = f2bf(fV[i][2]); b.w = f2bf(fV[i][3]);
            *reinterpret_cast<ushort4*>(
                &Xw[(w * 8 + rV) * XPAD + 64 + kind2 * 64 + (l & 15) * 4]) = b;
        }
    };

    // ---- prologue: stage tile 0; prefetch idx for tile 1 ----
    {
        int idx0 = load_idx(block0);
        issueEV(block0, idx0);
        write_lds(0);
    }
    int idxNext = (T_TILES > 1) ? load_idx(block0 + 64) : 0;
    BAR_LDS();

#pragma unroll 1
    for (int t = 0; t < T_TILES; ++t) {
        const long tb = block0 + (long)t * 64;
        const int xb = t & 1;

        if (t + 1 < T_TILES) issueEV(tb + 64, idxNext);  // counted vmcnt only
        if (t + 2 < T_TILES) idxNext = load_idx(tb + 128);

        const unsigned short* Xs = (const unsigned short*)(smem + xb * XBUF_SZ);
        unsigned char* Hb = smem + HS_OFF + xb * HBUF_SZ;

        f32x4 acc[2][4];
#pragma unroll
        for (int a = 0; a < 2; ++a)
#pragma unroll
            for (int b = 0; b < 4; ++b)
                acc[a][b] = (f32x4){0.f, 0.f, 0.f, 0.f};

        // ---- Layer 1: 3 phases of {8 reads -> BAR -> lgkm0 -> 16 MFMA -> BAR} ----
#pragma unroll
        for (int ph = 0; ph < 3; ++ph) {
            const int kb0 = ph * 2;
            short8 bx[2][4];
#pragma unroll
            for (int k = 0; k < 2; ++k)
#pragma unroll
                for (int mt = 0; mt < 4; ++mt)
                    bx[k][mt] = *reinterpret_cast<const short8*>(
                        &Xs[(mt * 16 + lm) * XPAD + (kb0 + k) * 32 + lg * 8]);
            BAR();
            LGKM0();
            __builtin_amdgcn_s_setprio(1);
#pragma unroll
            for (int k = 0; k < 2; ++k)
#pragma unroll
                for (int nt = 0; nt < 2; ++nt)
#pragma unroll
                    for (int mt = 0; mt < 4; ++mt)
                        acc[nt][mt] = __builtin_amdgcn_mfma_f32_16x16x32_bf16(
                            wA1[kb0 + k][nt], bx[k][mt], acc[nt][mt], 0, 0, 0);
            __builtin_amdgcn_s_setprio(0);
            BAR();
        }

        // ---- epilogue/staging phase ----
        // epi1: +b1, relu, bf16 -> Hs[xb] (XOR-swizzled)
#pragma unroll
        for (int nt = 0; nt < 2; ++nt) {
            int n0 = w * 32 + nt * 16 + lg * 4;
            float4 bv = *reinterpret_cast<const float4*>(b1 + n0);
#pragma unroll
            for (int mt = 0; mt < 4; ++mt) {
                f32x4 a = acc[nt][mt];
                ushort4 hb;
                hb.x = f2bf(fmaxf(a[0] + bv.x, 0.f));
                hb.y = f2bf(fmaxf(a[1] + bv.y, 0.f));
                hb.z = f2bf(fmaxf(a[2] + bv.z, 0.f));
                hb.w = f2bf(fmaxf(a[3] + bv.w, 0.f));
                int m = mt * 16 + lm;
                int addr = m * 512 + ((n0 * 2) ^ (lm << 4));
                *reinterpret_cast<ushort4*>(Hb + addr) = hb;
            }
        }
        if (t + 1 < T_TILES) write_lds(xb ^ 1);          // Xs[(t+1)&1]
        BAR_LDS();                                       // drain writes, align

        // ---- Layer 2: 4 phases; acc reused ----
#pragma unroll
        for (int a = 0; a < 2; ++a)
#pragma unroll
            for (int b = 0; b < 4; ++b)
                acc[a][b] = (f32x4){0.f, 0.f, 0.f, 0.f};

#pragma unroll
        for (int ph = 0; ph < 4; ++ph) {
            const int kb0 = ph * 2;
            short8 bh[2][4];
#pragma unroll
            for (int k = 0; k < 2; ++k)
#pragma unroll
                for (int mt = 0; mt < 4; ++mt) {
                    int m = mt * 16 + lm;
                    int addr = m * 512 + ((((kb0 + k) * 32 + lg * 8) * 2) ^ (lm << 4));
                    bh[k][mt] = *reinterpret_cast<const short8*>(Hb + addr);
                }
            BAR();
            LGKM0();
            __builtin_amdgcn_s_setprio(1);
#pragma unroll
            for (int k = 0; k < 2; ++k)
#pragma unroll
                for (int ot = 0; ot < 2; ++ot)
#pragma unroll
                    for (int mt = 0; mt < 4; ++mt)
                        acc[ot][mt] = __builtin_amdgcn_mfma_f32_16x16x32_bf16(
                            wA2[kb0 + k][ot], bh[k][mt], acc[ot][mt], 0, 0, 0);
            __builtin_amdgcn_s_setprio(0);
            BAR();
        }

        // epi2: +b2, coalesced NT f32x4 store (never waited in-loop)
#pragma unroll
        for (int ot = 0; ot < 2; ++ot) {
            int o0 = w * 32 + ot * 16 + lg * 4;
            float4 bv = *reinterpret_cast<const float4*>(b2 + o0);
#pragma unroll
            for (int mt = 0; mt < 4; ++mt) {
                f32x4 a = acc[ot][mt];
                f32x4 r;
                r[0] = a[0] + bv.x;
                r[1] = a[1] + bv.y;
                r[2] = a[2] + bv.z;
                r[3] = a[3] + bv.w;
                __builtin_nontemporal_store(r, reinterpret_cast<f32x4*>(
                    out + (size_t)(tb + mt * 16 + lm) * HID_C + o0));
            }
        }
    }
}

extern "C" void kernel_launch(void* const* d_in, const int* in_sizes, int n_in,
                              void* d_out, int out_size, void* d_ws, size_t ws_size,
                              hipStream_t stream) {
    const float* E  = (const float*)d_in[0];
    const float* V  = (const float*)d_in[1];
    const int*   ei = (const int*)d_in[2];   // [2][N_EDGES] int32
    const float* W1 = (const float*)d_in[3];
    const float* b1 = (const float*)d_in[4];
    const float* W2 = (const float*)d_in[5];
    const float* b2 = (const float*)d_in[6];
    float* out = (float*)d_out;

    unsigned short* W1T = (unsigned short*)d_ws;                 // 256*192 bf16
    unsigned short* W2T = W1T + IN_DIM_C * HID_C;                // 256*256 bf16

    const int prep_total = IN_DIM_C * HID_C + HID_C * HID_C;     // 114688
    prep_weights_kernel<<<(prep_total + 255) / 256, 256, 0, stream>>>(W1, W2, W1T, W2T);

    const int nblocks = N_EDGES_C / (64 * T_TILES);              // 3125
    edge_mlp_kernel<<<nblocks, 512, 0, stream>>>(
        E, V, ei, ei + N_EDGES_C, W1T, b1, W2T, b2, out);
}